// Round 3
// baseline (711.000 us; speedup 1.0000x reference)
//
#include <hip/hip_runtime.h>
#include <cstdint>
#include <cstddef>

// ---------------------------------------------------------------------------
// Pointer-network decoder: B=128 batches decode T=32 steps over N=512 nodes.
// Round 3: a PAIR of blocks per batch (256 blocks x 512 threads -> all 256
// CUs). Each block owns 256 nodes: LSTM computed redundantly (no sync needed
// for it), score/gumbel/argmax work halves per CU. One inter-block handoff
// per step via agent-scope atomics in ws (slots alias W1T, rewritten by the
// setup kernels each launch so stale flags can't survive graph replays).
// Score summation order kept bit-identical to round 2 (absmax 0.0).
// ---------------------------------------------------------------------------

constexpr int B = 128, N = 512, H = 128, T = 32;
constexpr int G4 = 4 * H;  // 512
constexpr float TINYF = 1.17549435e-38f;   // np.finfo(float32).tiny
constexpr uint32_t FLAG_BASE = 0x5AFE0000u;  // never a W1 float / 0xAA poison

// ---- JAX threefry2x32 block cipher (20 rounds) ----------------------------
__host__ __device__ inline uint32_t rotl32(uint32_t v, int d) {
  return (v << d) | (v >> (32 - d));
}

__host__ __device__ inline void tf2x32(uint32_t k0, uint32_t k1,
                                       uint32_t x0, uint32_t x1,
                                       uint32_t& o0, uint32_t& o1) {
  uint32_t ks2 = k0 ^ k1 ^ 0x1BD11BDAu;
  x0 += k0; x1 += k1;
#define TF_R(r) x0 += x1; x1 = rotl32(x1, (r)); x1 ^= x0;
  TF_R(13) TF_R(15) TF_R(26) TF_R(6)
  x0 += k1; x1 += ks2 + 1u;
  TF_R(17) TF_R(29) TF_R(16) TF_R(24)
  x0 += ks2; x1 += k0 + 2u;
  TF_R(13) TF_R(15) TF_R(26) TF_R(6)
  x0 += k0; x1 += k1 + 3u;
  TF_R(17) TF_R(29) TF_R(16) TF_R(24)
  x0 += k1; x1 += ks2 + 4u;
  TF_R(13) TF_R(15) TF_R(26) TF_R(6)
  x0 += ks2; x1 += k0 + 5u;
#undef TF_R
  o0 = x0; o1 = x1;
}

struct KeyArgs { uint32_t k[2 * T]; };  // per-step subkeys, 256 B by value

// Host-side key chain (partitionable split): key0 = (0,42);
// new_key = E_key(0,0), sub = E_key(0,1).
static KeyArgs make_subkeys() {
  KeyArgs ka;
  uint32_t k0 = 0u, k1 = 42u;
  for (int t = 0; t < T; ++t) {
    uint32_t n0, n1, s0, s1;
    tf2x32(k0, k1, 0u, 0u, n0, n1);
    tf2x32(k0, k1, 0u, 1u, s0, s1);
    ka.k[2 * t] = s0; ka.k[2 * t + 1] = s1;
    k0 = n0; k1 = n1;
  }
  return ka;
}

// 32-bit draw i (of 65536) for this step's subkey: w0^w1 of E_sub(0, i)
__device__ inline uint32_t gumbel_bits(uint32_t sk0, uint32_t sk1, int i) {
  uint32_t o0, o1;
  tf2x32(sk0, sk1, 0u, (uint32_t)i, o0, o1);
  return o0 ^ o1;
}

// fast tanh for the score hot loop; abs err ~2e-7 (clamp avoids inf/inf NaN)
__device__ inline float fast_tanh(float x) {
  float cx = fminf(9.0f, fmaxf(-9.0f, x));
  float t = __expf(2.0f * cx);
  return (t - 1.0f) * __builtin_amdgcn_rcpf(t + 1.0f);
}

// agent-scope atomic helpers (cross-XCD safe handoff)
__device__ inline void ag_store(uint32_t* p, uint32_t v) {
  __hip_atomic_store(p, v, __ATOMIC_RELAXED, __HIP_MEMORY_SCOPE_AGENT);
}
__device__ inline uint32_t ag_load(const uint32_t* p) {
  return __hip_atomic_load(p, __ATOMIC_RELAXED, __HIP_MEMORY_SCOPE_AGENT);
}

// ---- setup kernel 1: transpose weights for coalesced access ---------------
__global__ void k_transpose(const float* __restrict__ Wih, const float* __restrict__ Whh,
                            const float* __restrict__ W2, const float* __restrict__ W1,
                            float* __restrict__ WihT, float* __restrict__ WhhT,
                            float* __restrict__ W2T, float* __restrict__ W1T) {
  int i = blockIdx.x * blockDim.x + threadIdx.x;
  if (i < H * G4) {
    int h = i >> 9, j = i & (G4 - 1);
    WihT[i] = Wih[j * H + h];
  } else if (i < 2 * H * G4) {
    int q = i - H * G4; int h = q >> 9, j = q & (G4 - 1);
    WhhT[q] = Whh[j * H + h];
  } else if (i < 2 * H * G4 + H * H) {
    int q = i - 2 * H * G4; int h = q >> 7, k = q & (H - 1);
    W2T[q] = W2[k * H + h];
  } else if (i < 2 * H * G4 + 2 * H * H) {
    int q = i - 2 * H * G4 - H * H; int h = q >> 7, k = q & (H - 1);
    W1T[q] = W1[k * H + h];
  }
}

// ---- setup kernel 2: encT2[b,k,n] = sum_h enc[b,n,h] * W1[k,h] ------------
// (k-major output for the decode score SGEMV). 16 enc rows staged in LDS;
// 256 threads = 128 k x 2 n-groups; per-thread 8 consecutive n -> 2x float4.
__global__ __launch_bounds__(256) void k_enc_trans(const float* __restrict__ enc,
                                                   const float* __restrict__ W1T,
                                                   float* __restrict__ encT2) {
  __shared__ __align__(16) float es[16 * 128];  // 8 KB
  int blk = blockIdx.x;
  int b = blk >> 5;               // 32 blocks per batch
  int n0 = (blk & 31) << 4;       // 16 rows
  const float* src = enc + ((size_t)b * N + n0) * H;
  for (int i = threadIdx.x; i < 16 * 128; i += 256) es[i] = src[i];
  __syncthreads();
  int k = threadIdx.x & 127, ng = threadIdx.x >> 7;
  float acc[8] = {0.f, 0.f, 0.f, 0.f, 0.f, 0.f, 0.f, 0.f};
  for (int h = 0; h < H; h += 4) {
    float w0 = W1T[(h + 0) * H + k];   // coalesced (lanes = consecutive k)
    float w1 = W1T[(h + 1) * H + k];
    float w2 = W1T[(h + 2) * H + k];
    float w3 = W1T[(h + 3) * H + k];
#pragma unroll
    for (int j = 0; j < 8; ++j) {
      const float4 e = *(const float4*)&es[(ng * 8 + j) * 128 + h];  // broadcast
      acc[j] += w0 * e.x + w1 * e.y + w2 * e.z + w3 * e.w;
    }
  }
  float* dst = encT2 + (size_t)b * H * N + (size_t)k * N + n0 + ng * 8;
  ((float4*)dst)[0] = make_float4(acc[0], acc[1], acc[2], acc[3]);
  ((float4*)dst)[1] = make_float4(acc[4], acc[5], acc[6], acc[7]);
}

// ---- main fused decoder: block pair per batch, 512 threads each -----------
__global__ __launch_bounds__(512) void k_decode(
    const float* __restrict__ enc, const float* __restrict__ encT2,
    const float* __restrict__ WihT, const float* __restrict__ WhhT,
    const float* __restrict__ W2T,
    const float* __restrict__ bih, const float* __restrict__ bhh,
    const float* __restrict__ v,
    KeyArgs keys, uint32_t* __restrict__ slots, float* __restrict__ out) {
  __shared__ __align__(16) float xs[H];     // dec_input
  __shared__ __align__(16) float hs[H];     // hx
  __shared__ __align__(16) float cs[H];     // cx
  __shared__ __align__(16) float dt[H];     // dec_trans = hx @ W2^T
  __shared__ __align__(16) float vv[H];
  __shared__ __align__(16) float bsum[G4];  // b_ih + b_hh
  __shared__ float gates[G4];
  __shared__ float pdt[4][H];               // dt partials (and init-mean partials)
  __shared__ float ps[2][256];              // score k-split partials (my 256 n)
  __shared__ float sc[256];                 // masked scores (my half)
  __shared__ float wr_z[4], wr_m[4], wr_s[4];
  __shared__ int wr_i[4];
  __shared__ int s_idx;

  const int tid = threadIdx.x;
  const int bq = blockIdx.x >> 1;   // batch
  const int nh = blockIdx.x & 1;    // my n-half: nodes [nh*256, nh*256+256)
  const int lane = tid & 63;
  const int wave = tid >> 6;

  // ---- init: dec_input = mean_n enc[b,n,:]; h = c = 0 (redundant in pair) --
  {
    int h = tid & 127, part = tid >> 7;
    float s = 0.f;
    const float* p = enc + ((size_t)bq * N + part * 128) * H + h;
#pragma unroll 8
    for (int n = 0; n < 128; ++n) s += p[(size_t)n * H];  // coalesced across h
    pdt[part][h] = s;
    bsum[tid] = bih[tid] + bhh[tid];
  }
  if (tid < 128) { hs[tid] = 0.f; cs[tid] = 0.f; vv[tid] = v[tid]; }
  __syncthreads();
  if (tid < 128)
    xs[tid] = (pdt[0][tid] + pdt[1][tid] + pdt[2][tid] + pdt[3][tid]) * (1.0f / N);
  bool masked = false;  // thread tid<256 owns node nh*256+tid
  __syncthreads();

  uint32_t* my = slots + (((bq << 1) | nh) << 3);
  uint32_t* th = slots + (((bq << 1) | (nh ^ 1)) << 3);

  for (int t = 0; t < T; ++t) {
    // --- P1: gates[j] (j = tid), full h, 4 indep chains; same association as
    //     round 2's ((x0+h0)+(x1+h1)) split-K form (redundant across pair) ----
    {
      const float* wi = WihT + tid;  // WihT[h][j], lanes = consecutive j
      const float* wh = WhhT + tid;
      float ax0 = 0.f, ah0 = 0.f, ax1 = 0.f, ah1 = 0.f;
#pragma unroll 8
      for (int h = 0; h < 64; ++h) {
        ax0 += wi[h * G4] * xs[h];
        ah0 += wh[h * G4] * hs[h];
        ax1 += wi[(64 + h) * G4] * xs[64 + h];
        ah1 += wh[(64 + h) * G4] * hs[64 + h];
      }
      gates[tid] = (ax0 + ah0) + (ax1 + ah1);
    }
    __syncthreads();
    // --- P2: cell update (torch gate order i,f,g,o) -------------------------
    if (tid < 128) {
      float gi = gates[tid] + bsum[tid];
      float gf = gates[H + tid] + bsum[H + tid];
      float gg = gates[2 * H + tid] + bsum[2 * H + tid];
      float go = gates[3 * H + tid] + bsum[3 * H + tid];
      gi = 1.0f / (1.0f + expf(-gi));
      gf = 1.0f / (1.0f + expf(-gf));
      gg = tanhf(gg);
      go = 1.0f / (1.0f + expf(-go));
      float c = gf * cs[tid] + gi * gg;
      cs[tid] = c;
      hs[tid] = go * tanhf(c);
    }
    __syncthreads();
    // --- P3: dt partials: k = tid&127, 32 h each ----------------------------
    {
      int k = tid & 127, part = tid >> 7;
      const float* w2 = W2T + (size_t)(part * 32) * H + k;
      const int hb = part * 32;
      float a = 0.f;
#pragma unroll 8
      for (int h = 0; h < 32; ++h) a += w2[h * H] * hs[hb + h];
      pdt[part][k] = a;
    }
    __syncthreads();
    if (tid < 128) dt[tid] = pdt[0][tid] + pdt[1][tid] + pdt[2][tid] + pdt[3][tid];
    __syncthreads();
    // --- P4: scores for MY 256 n: tid = kh*256 + ni; same k-split/accum
    //     pairing as round 2 -> bit-identical scores --------------------------
    {
      const int kh = tid >> 8, ni = tid & 255;
      const int kb = kh * 64;
      const float* ep = encT2 + (size_t)bq * (H * N) + (size_t)kb * N + nh * 256 + ni;
      float a0 = 0.f, a1 = 0.f;
#pragma unroll 8
      for (int kk = 0; kk < 64; kk += 2) {
        float e0 = ep[(size_t)kk * N];
        float e1 = ep[(size_t)(kk + 1) * N];
        a0 += vv[kb + kk] * fast_tanh(e0 + dt[kb + kk]);
        a1 += vv[kb + kk + 1] * fast_tanh(e1 + dt[kb + kk + 1]);
      }
      ps[kh][ni] = a0 + a1;
    }
    __syncthreads();
    // --- P5: mask, gumbel, per-wave argmax + max + local expsum (waves 0-3) -
    if (tid < 256) {
      const int ng = nh * 256 + tid;  // global node index
      float s = masked ? -INFINITY : (ps[0][tid] + ps[1][tid]);
      sc[tid] = s;
      uint32_t bits = gumbel_bits(keys.k[2 * t], keys.k[2 * t + 1], bq * N + ng);
      // XLA uniform(minval=tiny, maxval=1): bits->[1,2)->-1, +tiny, max
      float f = __uint_as_float((bits >> 9) | 0x3f800000u) - 1.0f;
      float u = fmaxf(TINYF, f + TINYF);
      float g = -logf(-logf(u));  // accurate logf (hw log2 too sloppy near u~1)
      float z = s + g;
      int zi = ng;
      float m = s;
#pragma unroll
      for (int d = 32; d >= 1; d >>= 1) {
        float oz = __shfl_xor(z, d);
        int oi = __shfl_xor(zi, d);
        float om = __shfl_xor(m, d);
        if (oz > z || (oz == z && oi < zi)) { z = oz; zi = oi; }  // first-idx ties
        m = fmaxf(m, om);
      }
      float e = expf(s - m);  // wave-local max; rescaled when combined
#pragma unroll
      for (int d = 32; d >= 1; d >>= 1) e += __shfl_xor(e, d);
      if (lane == 0) { wr_z[wave] = z; wr_i[wave] = zi; wr_m[wave] = m; wr_s[wave] = e; }
    }
    __syncthreads();
    // --- P5b: block-local combine, publish, partner handoff, final sample ---
    if (tid == 0) {
      float bz = wr_z[0]; int bi = wr_i[0]; float bm = wr_m[0];
#pragma unroll
      for (int w = 1; w < 4; ++w) {
        if (wr_z[w] > bz || (wr_z[w] == bz && wr_i[w] < bi)) { bz = wr_z[w]; bi = wr_i[w]; }
        bm = fmaxf(bm, wr_m[w]);
      }
      float es = wr_s[0] * expf(wr_m[0] - bm) + wr_s[1] * expf(wr_m[1] - bm)
               + wr_s[2] * expf(wr_m[2] - bm) + wr_s[3] * expf(wr_m[3] - bm);
      float scat = sc[bi - nh * 256];  // score at my argmax
      ag_store(my + 0, __float_as_uint(bz));
      ag_store(my + 1, (uint32_t)bi);
      ag_store(my + 2, __float_as_uint(bm));
      ag_store(my + 3, __float_as_uint(es));
      ag_store(my + 4, __float_as_uint(scat));
      __hip_atomic_store(my + 7, FLAG_BASE + (uint32_t)t,
                         __ATOMIC_RELEASE, __HIP_MEMORY_SCOPE_AGENT);
      while (__hip_atomic_load(th + 7, __ATOMIC_ACQUIRE, __HIP_MEMORY_SCOPE_AGENT)
             != FLAG_BASE + (uint32_t)t)
        __builtin_amdgcn_s_sleep(1);
      float oz = __uint_as_float(ag_load(th + 0));
      int oi = (int)ag_load(th + 1);
      float om = __uint_as_float(ag_load(th + 2));
      float oes = __uint_as_float(ag_load(th + 3));
      float oscat = __uint_as_float(ag_load(th + 4));
      bool iwin = (bz > oz) || (bz == oz && bi < oi);  // global first-idx ties
      int idx = iwin ? bi : oi;
      s_idx = idx;
      if (nh == 0) {
        float M = fmaxf(bm, om);
        float sum = es * expf(bm - M) + oes * expf(om - M);
        float scidx = iwin ? scat : oscat;
        float p = expf(scidx - M) / sum;
        out[(size_t)bq * T + t] = (float)idx;                       // tours [B,T]
        out[(size_t)B * T + (size_t)bq * T + t] = logf(p + 1e-9f);  // log_probs
      }
    }
    __syncthreads();
    // --- P6: mask update + next dec_input -----------------------------------
    if (tid < 256) {
      if (tid == s_idx - nh * 256) masked = true;
    } else if (tid < 384) {
      xs[tid - 256] = enc[((size_t)bq * N + s_idx) * H + (tid - 256)];
    }
    __syncthreads();
  }
}

// ---------------------------------------------------------------------------
extern "C" void kernel_launch(void* const* d_in, const int* in_sizes, int n_in,
                              void* d_out, int out_size, void* d_ws, size_t ws_size,
                              hipStream_t stream) {
  (void)in_sizes; (void)n_in; (void)out_size; (void)ws_size;
  const float* enc = (const float*)d_in[0];
  const float* Wih = (const float*)d_in[1];
  const float* Whh = (const float*)d_in[2];
  const float* bih = (const float*)d_in[3];
  const float* bhh = (const float*)d_in[4];
  const float* W1  = (const float*)d_in[5];
  const float* W2  = (const float*)d_in[6];
  const float* v   = (const float*)d_in[7];
  float* out = (float*)d_out;
  float* ws = (float*)d_ws;

  // ws layout (floats): WihT 65536 | WhhT 65536 | W2T 16384 | W1T 16384 | encT2 8388608
  float* WihT  = ws;
  float* WhhT  = ws + 65536;
  float* W2T   = ws + 131072;
  float* W1T   = ws + 147456;
  float* encT2 = ws + 163840;   // [b][k][n], ~33.5 MB
  // handoff slots alias W1T (only used by setup kernels, which rewrite it
  // every launch -> stale flags from prior replays are destroyed). 256 slots
  // x 8 u32 = 8 KB << 64 KB region. FLAG values never collide with W1 floats.
  uint32_t* slots = (uint32_t*)W1T;

  KeyArgs keys = make_subkeys();  // pure host arithmetic: capture-safe

  k_transpose<<<640, 256, 0, stream>>>(Wih, Whh, W2, W1, WihT, WhhT, W2T, W1T);
  k_enc_trans<<<B * N / 16, 256, 0, stream>>>(enc, W1T, encT2);
  k_decode<<<2 * B, 512, 0, stream>>>(enc, encT2, WihT, WhhT, W2T, bih, bhh, v,
                                      keys, slots, out);
}

// Round 5
// 628.653 us; speedup vs baseline: 1.1310x; 1.1310x over previous
//
#include <hip/hip_runtime.h>
#include <cstdint>
#include <cstddef>

// ---------------------------------------------------------------------------
// Pointer-network decoder: B=128 batches decode T=32 steps over N=512 nodes.
// Round 5 = round 4 with the k_setup grid bug fixed: enc_trans needs 4096
// blocks (32 per batch x 128 batches); round 4 launched only 512, leaving
// batches 16..127 with poisoned encT2 (the absmax-500 failure). Weight
// transposes ride on blocks 4096..4159.
// k_decode: 128 blocks x 1024 threads; encT2 cached in registers across the
// t-loop (P4 has zero global loads), gumbel table precomputed into LDS,
// no softmax max-shift, redundant per-thread argmax combine, deferred output
// stores, packed (x,h)/(dt,v) LDS operands, 7 barriers/step.
// All idx-feeding arithmetic keeps bit-identical association with round 2.
// ---------------------------------------------------------------------------

constexpr int B = 128, N = 512, H = 128, T = 32;
constexpr int G4 = 4 * H;  // 512
constexpr float TINYF = 1.17549435e-38f;  // np.finfo(float32).tiny

// ---- JAX threefry2x32 block cipher (20 rounds) ----------------------------
__host__ __device__ inline uint32_t rotl32(uint32_t v, int d) {
  return (v << d) | (v >> (32 - d));
}

__host__ __device__ inline void tf2x32(uint32_t k0, uint32_t k1,
                                       uint32_t x0, uint32_t x1,
                                       uint32_t& o0, uint32_t& o1) {
  uint32_t ks2 = k0 ^ k1 ^ 0x1BD11BDAu;
  x0 += k0; x1 += k1;
#define TF_R(r) x0 += x1; x1 = rotl32(x1, (r)); x1 ^= x0;
  TF_R(13) TF_R(15) TF_R(26) TF_R(6)
  x0 += k1; x1 += ks2 + 1u;
  TF_R(17) TF_R(29) TF_R(16) TF_R(24)
  x0 += ks2; x1 += k0 + 2u;
  TF_R(13) TF_R(15) TF_R(26) TF_R(6)
  x0 += k0; x1 += k1 + 3u;
  TF_R(17) TF_R(29) TF_R(16) TF_R(24)
  x0 += k1; x1 += ks2 + 4u;
  TF_R(13) TF_R(15) TF_R(26) TF_R(6)
  x0 += ks2; x1 += k0 + 5u;
#undef TF_R
  o0 = x0; o1 = x1;
}

struct KeyArgs { uint32_t k[2 * T]; };  // per-step subkeys, 256 B by value

// Host-side key chain (partitionable split): key0 = (0,42);
// new_key = E_key(0,0), sub = E_key(0,1).
static KeyArgs make_subkeys() {
  KeyArgs ka;
  uint32_t k0 = 0u, k1 = 42u;
  for (int t = 0; t < T; ++t) {
    uint32_t n0, n1, s0, s1;
    tf2x32(k0, k1, 0u, 0u, n0, n1);
    tf2x32(k0, k1, 0u, 1u, s0, s1);
    ka.k[2 * t] = s0; ka.k[2 * t + 1] = s1;
    k0 = n0; k1 = n1;
  }
  return ka;
}

// 32-bit draw i (of 65536) for this step's subkey: w0^w1 of E_sub(0, i)
__device__ inline uint32_t gumbel_bits(uint32_t sk0, uint32_t sk1, int i) {
  uint32_t o0, o1;
  tf2x32(sk0, sk1, 0u, (uint32_t)i, o0, o1);
  return o0 ^ o1;
}

// fast tanh for the score hot loop; abs err ~2e-7 (clamp avoids inf/inf NaN)
__device__ inline float fast_tanh(float x) {
  float cx = fminf(9.0f, fmaxf(-9.0f, x));
  float t = __expf(2.0f * cx);
  return (t - 1.0f) * __builtin_amdgcn_rcpf(t + 1.0f);
}

// ---- setup: blocks 0..4095 = enc_trans (W1 self-transposed into LDS);
//             blocks 4096..4159 = Wih/Whh/W2 transposes (grid-stride) -------
__global__ __launch_bounds__(256) void k_setup(
    const float* __restrict__ enc, const float* __restrict__ W1,
    const float* __restrict__ Wih, const float* __restrict__ Whh,
    const float* __restrict__ W2,
    float* __restrict__ encT2, float* __restrict__ WihT,
    float* __restrict__ WhhT, float* __restrict__ W2T) {
  __shared__ float w1t[128 * 129];              // padded transpose, 66 KB
  __shared__ __align__(16) float es[16 * 128];  // 8 KB

  if (blockIdx.x >= 4096) {
    int base = (blockIdx.x - 4096) * 256 + threadIdx.x;
    const int stride = 64 * 256;
    for (int i = base; i < H * G4; i += stride) {
      int h = i >> 9, j = i & (G4 - 1);
      WihT[i] = Wih[j * H + h];
      WhhT[i] = Whh[j * H + h];
    }
    for (int i = base; i < H * H; i += stride) {
      int h = i >> 7, k = i & (H - 1);
      W2T[i] = W2[k * H + h];
    }
    return;
  }
  // load & transpose W1 into LDS (padded stride 129 -> conflict-free)
  for (int i = threadIdx.x; i < H * H; i += 256) {
    int k = i >> 7, h = i & 127;
    w1t[h * 129 + k] = W1[i];
  }
  int blk = blockIdx.x;
  int b = blk >> 5;               // 32 blocks per batch -> b in [0,127]
  int n0 = (blk & 31) << 4;       // 16 rows
  const float* src = enc + ((size_t)b * N + n0) * H;
  for (int i = threadIdx.x; i < 16 * 128; i += 256) es[i] = src[i];
  __syncthreads();
  int k = threadIdx.x & 127, ng = threadIdx.x >> 7;
  float acc[8] = {0.f, 0.f, 0.f, 0.f, 0.f, 0.f, 0.f, 0.f};
  for (int h = 0; h < H; h += 4) {
    float w0 = w1t[(h + 0) * 129 + k];
    float w1 = w1t[(h + 1) * 129 + k];
    float w2 = w1t[(h + 2) * 129 + k];
    float w3 = w1t[(h + 3) * 129 + k];
#pragma unroll
    for (int j = 0; j < 8; ++j) {
      const float4 e = *(const float4*)&es[(ng * 8 + j) * 128 + h];  // broadcast
      acc[j] += w0 * e.x + w1 * e.y + w2 * e.z + w3 * e.w;
    }
  }
  float* dst = encT2 + (size_t)b * H * N + (size_t)k * N + n0 + ng * 8;
  ((float4*)dst)[0] = make_float4(acc[0], acc[1], acc[2], acc[3]);
  ((float4*)dst)[1] = make_float4(acc[4], acc[5], acc[6], acc[7]);
}

// ---- main fused decoder: 1 block per batch, 1024 threads, er in VGPRs -----
__global__ __launch_bounds__(1024, 4) void k_decode(
    const float* __restrict__ enc, const float* __restrict__ encT2,
    const float* __restrict__ WihT, const float* __restrict__ WhhT,
    const float* __restrict__ W2T,
    const float* __restrict__ bih, const float* __restrict__ bhh,
    const float* __restrict__ v,
    KeyArgs keys, float* __restrict__ out) {
  __shared__ float2 xh[H];                  // (dec_input, hx) packed
  __shared__ float cs[H];
  __shared__ float2 dv[H];                  // (dec_trans, v) packed
  __shared__ __align__(16) float bsum[G4];  // b_ih + b_hh
  __shared__ float pg[2][G4];               // gate split-K partials
  __shared__ float pdt[4][H];               // dt partials (and init-mean)
  __shared__ float ps[2][N];                // score k-split partials
  __shared__ float sc[N];                   // masked scores
  __shared__ float gb[T * N];               // gumbel table, 64 KB
  __shared__ float wr_z[8], wr_s[8];
  __shared__ int wr_i[8];
  __shared__ float outb[2][T];              // deferred outputs

  const int tid = threadIdx.x;
  const int b = blockIdx.x;
  const int lane = tid & 63;
  const int wave = tid >> 6;
  const int kh = tid >> 9;      // k-half (P1 h-half, P4 k-half)
  const int nn = tid & 511;     // owned gate j / score n

  // ---- init-mean partials (same association as round 2) ----
  if (tid < 512) {
    int h = tid & 127, part = tid >> 7;
    float s = 0.f;
    const float* p = enc + ((size_t)b * N + part * 128) * H + h;
#pragma unroll 8
    for (int n = 0; n < 128; ++n) s += p[(size_t)n * H];  // coalesced across h
    pdt[part][h] = s;
    bsum[tid] = bih[tid] + bhh[tid];
  }
  // ---- gumbel table: all (t,n) for this batch; VALU overlaps mean loads ----
#pragma unroll
  for (int q = 0; q < 16; ++q) {
    int idx = q * 1024 + tid;           // 0..16383
    int tt = idx >> 9, n = idx & 511;   // tt wave-uniform (64 | 512)
    uint32_t bits = gumbel_bits(keys.k[2 * tt], keys.k[2 * tt + 1], b * N + n);
    // XLA uniform(minval=tiny, maxval=1): bits->[1,2)->-1, +tiny, max
    float f = __uint_as_float((bits >> 9) | 0x3f800000u) - 1.0f;
    float u = fmaxf(TINYF, f + TINYF);
    gb[tt * N + n] = -logf(-logf(u));   // same instr sequence as rounds 1-3
  }
  if (tid < 128) { cs[tid] = 0.f; dv[tid] = make_float2(0.f, v[tid]); }
  // ---- er: this thread's 64 t-invariant encT2 values -> registers ----
  float er[64];
  {
    const float* ep = encT2 + (size_t)b * (H * N) + (size_t)(kh * 64) * N + nn;
#pragma unroll
    for (int kk = 0; kk < 64; ++kk) er[kk] = ep[(size_t)kk * N];
  }
  __syncthreads();
  if (tid < 128)
    xh[tid] = make_float2(
        (pdt[0][tid] + pdt[1][tid] + pdt[2][tid] + pdt[3][tid]) * (1.0f / N), 0.f);
  bool masked = false;  // thread nn (tid<512) owns node nn
  __syncthreads();

  for (int t = 0; t < T; ++t) {
    // --- P1: gate partials (j = nn, h-range kh*64..+63); round-2 assoc ------
    {
      const int hb = kh * 64;
      const float* wi = WihT + (size_t)hb * G4 + nn;
      const float* wh = WhhT + (size_t)hb * G4 + nn;
      float a0 = 0.f, a1 = 0.f;
#pragma unroll 8
      for (int h = 0; h < 64; ++h) {
        float2 xhv = xh[hb + h];  // one b64 broadcast for (x, h)
        a0 += wi[h * G4] * xhv.x;
        a1 += wh[h * G4] * xhv.y;
      }
      pg[kh][nn] = a0 + a1;
    }
    __syncthreads();
    // --- P2: cell update (torch gate order i,f,g,o) -------------------------
    if (tid < 128) {
      float gi = pg[0][tid] + pg[1][tid] + bsum[tid];
      float gf = pg[0][H + tid] + pg[1][H + tid] + bsum[H + tid];
      float gg = pg[0][2 * H + tid] + pg[1][2 * H + tid] + bsum[2 * H + tid];
      float go = pg[0][3 * H + tid] + pg[1][3 * H + tid] + bsum[3 * H + tid];
      gi = 1.0f / (1.0f + expf(-gi));
      gf = 1.0f / (1.0f + expf(-gf));
      gg = tanhf(gg);
      go = 1.0f / (1.0f + expf(-go));
      float c = gf * cs[tid] + gi * gg;
      cs[tid] = c;
      xh[tid].y = go * tanhf(c);
    }
    __syncthreads();
    // --- P3a: dt partials (k = tid&127, 32 h each); round-2 assoc -----------
    if (tid < 512) {
      int k = tid & 127, part = tid >> 7;
      const float* w2 = W2T + (size_t)(part * 32) * H + k;
      const int hb = part * 32;
      float a = 0.f;
#pragma unroll 8
      for (int h = 0; h < 32; ++h) a += w2[h * H] * xh[hb + h].y;
      pdt[part][k] = a;
    }
    __syncthreads();
    // --- P3b: dt reduce -----------------------------------------------------
    if (tid < 128)
      dv[tid].x = pdt[0][tid] + pdt[1][tid] + pdt[2][tid] + pdt[3][tid];
    __syncthreads();
    // --- P4: scores, pure VALU (er in regs, dv broadcast); round-2 assoc ----
    {
      const int kb = kh * 64;
      float a0 = 0.f, a1 = 0.f;
#pragma unroll
      for (int kk = 0; kk < 64; kk += 2) {
        float2 d0 = dv[kb + kk];
        float2 d1 = dv[kb + kk + 1];
        a0 += d0.y * fast_tanh(er[kk] + d0.x);
        a1 += d1.y * fast_tanh(er[kk + 1] + d1.x);
      }
      ps[kh][nn] = a0 + a1;
    }
    __syncthreads();
    // --- P5: mask + gumbel(z) + per-wave argmax + unshifted expsum ----------
    if (tid < 512) {
      float s = masked ? -INFINITY : (ps[0][tid] + ps[1][tid]);
      sc[tid] = s;
      float z = s + gb[t * N + tid];
      int zi = tid;
#pragma unroll
      for (int d = 32; d >= 1; d >>= 1) {
        float oz = __shfl_xor(z, d);
        int oi = __shfl_xor(zi, d);
        if (oz > z || (oz == z && oi < zi)) { z = oz; zi = oi; }  // first-idx ties
      }
      float e = expf(s);  // scores bounded (|s|<~6): no shift needed; exp(-inf)=0
#pragma unroll
      for (int d = 32; d >= 1; d >>= 1) e += __shfl_xor(e, d);
      if (lane == 0) { wr_z[wave] = z; wr_i[wave] = zi; wr_s[wave] = e; }
    }
    __syncthreads();
    // --- P6: redundant combine (all threads), mask, xs gather, outputs ------
    {
      float bz = wr_z[0]; int bi = wr_i[0];
#pragma unroll
      for (int w = 1; w < 8; ++w) {
        float wz = wr_z[w]; int wj = wr_i[w];
        if (wz > bz || (wz == bz && wj < bi)) { bz = wz; bi = wj; }
      }
      if (tid == bi) masked = true;  // owner thread (tid<512)
      if (tid >= 512 && tid < 640)
        xh[tid - 512].x = enc[((size_t)b * N + bi) * H + (tid - 512)];
      if (tid == 0) {
        float S = ((((((wr_s[0] + wr_s[1]) + wr_s[2]) + wr_s[3]) + wr_s[4])
                    + wr_s[5]) + wr_s[6]) + wr_s[7];
        float p = expf(sc[bi]) / S;
        outb[0][t] = (float)bi;
        outb[1][t] = logf(p + 1e-9f);  // LDS write: no vmcnt drain at barrier
      }
    }
    __syncthreads();
  }
  // ---- epilogue: flush deferred outputs ----
  if (tid < T) {
    out[(size_t)b * T + tid] = outb[0][tid];
    out[(size_t)B * T + (size_t)b * T + tid] = outb[1][tid];
  }
}

// ---------------------------------------------------------------------------
extern "C" void kernel_launch(void* const* d_in, const int* in_sizes, int n_in,
                              void* d_out, int out_size, void* d_ws, size_t ws_size,
                              hipStream_t stream) {
  (void)in_sizes; (void)n_in; (void)out_size; (void)ws_size;
  const float* enc = (const float*)d_in[0];
  const float* Wih = (const float*)d_in[1];
  const float* Whh = (const float*)d_in[2];
  const float* bih = (const float*)d_in[3];
  const float* bhh = (const float*)d_in[4];
  const float* W1  = (const float*)d_in[5];
  const float* W2  = (const float*)d_in[6];
  const float* v   = (const float*)d_in[7];
  float* out = (float*)d_out;
  float* ws = (float*)d_ws;

  // ws layout (floats): WihT 65536 | WhhT 65536 | W2T 16384 | encT2 8388608
  float* WihT  = ws;
  float* WhhT  = ws + 65536;
  float* W2T   = ws + 131072;
  float* encT2 = ws + 147456;   // [b][k][n], ~33.5 MB

  KeyArgs keys = make_subkeys();  // pure host arithmetic: capture-safe

  // 4096 enc_trans blocks (32/batch x 128) + 64 transpose blocks
  k_setup<<<4160, 256, 0, stream>>>(enc, W1, Wih, Whh, W2, encT2, WihT, WhhT, W2T);
  k_decode<<<B, 1024, 0, stream>>>(enc, encT2, WihT, WhhT, W2T, bih, bhh, v,
                                   keys, out);
}